// Round 1
// baseline (1403.328 us; speedup 1.0000x reference)
//
#include <hip/hip_runtime.h>
#include <hip/hip_fp16.h>

// 3x3 stride-1 pad-1 conv, NCHW fp32 in/out, computed via per-tap MFMA f16.
// B=8, CIN=COUT=16, H=W=1024.
//
// Per block: one (b, h) and a 256-pixel row segment; all 16 couts.
// LDS stages x[b, :, h-1..h+1, w0-1..w0+256] as f16, layout [3][258][20]
// (cin innermost, padded 16->20 halfs = 40B stride: 8B-aligned ds_read_b64
// A-fragments, bank stride 10 -> 16 distinct even banks across 16 lanes).
//
// MFMA mapping (16x16x16 f16, verified layouts from guide):
//   A[m=lane&15][k=4*(lane>>4)+j]   m = pixel-in-tile, k = cin
//   B[k=4*(lane>>4)+j][n=lane&15]   n = cout
//   D[row=m=4*(lane>>4)+reg][col=n=lane&15]
// => each lane's 4 acc regs are 4 consecutive pixels -> float4 store.

typedef _Float16 f16x4 __attribute__((ext_vector_type(4)));
typedef float f32x4 __attribute__((ext_vector_type(4)));

#define B_N   8
#define C_IN  16
#define C_OUT 16
#define H_N   1024
#define W_N   1024
#define TILE_W 256
#define LDS_W (TILE_W + 2)   // 258 (halo)
#define CPAD  20             // 16 cin + 4 pad halfs -> 40B per pixel

__global__ __launch_bounds__(256) void conv3x3_mfma(
    const float* __restrict__ x, const float* __restrict__ wt,
    float* __restrict__ out)
{
    __shared__ _Float16 s_x[3][LDS_W][CPAD];

    const int wblk = blockIdx.x;      // 0..3
    const int h    = blockIdx.y;      // 0..1023
    const int b    = blockIdx.z;      // 0..7
    const int w0   = wblk * TILE_W;
    const int tid  = threadIdx.x;
    const int lane = tid & 63;
    const int q    = lane >> 4;       // 0..3
    const int ln   = lane & 15;       // 0..15
    const int wave = tid >> 6;        // 0..3

    // ---- B fragments: 9 taps, f16, in registers ----
    f16x4 bfrag[9];
#pragma unroll
    for (int kh = 0; kh < 3; ++kh) {
#pragma unroll
        for (int kw = 0; kw < 3; ++kw) {
            f16x4 f;
#pragma unroll
            for (int j = 0; j < 4; ++j) {
                const int cin = 4 * q + j;
                f[j] = (_Float16)wt[((ln * C_IN + cin) * 3 + kh) * 3 + kw];
            }
            bfrag[kh * 3 + kw] = f;
        }
    }

    // ---- stage x tile to LDS: 3 rows x 258 cols x 16 cin ----
    // flat idx = (r*C_IN + c)*LDS_W + i ; coalesced along i (=w)
    const int total = 3 * C_IN * LDS_W;  // 12384
    for (int idx = tid; idx < total; idx += 256) {
        const int r   = idx / (C_IN * LDS_W);
        const int rem = idx - r * (C_IN * LDS_W);
        const int c   = rem / LDS_W;
        const int i   = rem - c * LDS_W;
        const int gh  = h - 1 + r;
        const int gw  = w0 - 1 + i;
        float v = 0.0f;
        if ((unsigned)gh < (unsigned)H_N && (unsigned)gw < (unsigned)W_N)
            v = x[(((size_t)b * C_IN + c) * H_N + gh) * W_N + gw];
        s_x[r][i][c] = (_Float16)v;
    }
    __syncthreads();

    // ---- compute: 4 m-tiles of 16 pixels per wave ----
#pragma unroll
    for (int mt = 0; mt < 4; ++mt) {
        const int base = wave * 64 + mt * 16;   // pixel base within 256-tile
        f32x4 acc = {0.f, 0.f, 0.f, 0.f};
#pragma unroll
        for (int kh = 0; kh < 3; ++kh) {
#pragma unroll
            for (int kw = 0; kw < 3; ++kw) {
                const f16x4 a =
                    *(const f16x4*)&s_x[kh][base + ln + kw][4 * q];
                acc = __builtin_amdgcn_mfma_f32_16x16x16f16(
                    a, bfrag[kh * 3 + kw], acc, 0, 0, 0);
            }
        }
        // store: lane's 4 regs = pixels base+4q .. base+4q+3, cout = ln
        const int wout = w0 + base + 4 * q;
        f32x4* dst = (f32x4*)&out[(((size_t)b * C_OUT + ln) * H_N + h) * W_N + wout];
        *dst = acc;
    }
}

extern "C" void kernel_launch(void* const* d_in, const int* in_sizes, int n_in,
                              void* d_out, int out_size, void* d_ws, size_t ws_size,
                              hipStream_t stream) {
    const float* x  = (const float*)d_in[0];
    const float* wt = (const float*)d_in[1];
    float* out = (float*)d_out;
    dim3 grid(W_N / TILE_W, H_N, B_N);
    conv3x3_mfma<<<grid, 256, 0, stream>>>(x, wt, out);
}